// Round 6
// baseline (486.678 us; speedup 1.0000x reference)
//
#include <hip/hip_runtime.h>
#include <hip/hip_bf16.h>

#define NN 100000
#define NE 1600000
#define DIN 128
#define NG 512
#define MAXD 64
#define NTILE ((NN + 63) >> 6)  // 64-node tiles

typedef __attribute__((ext_vector_type(8))) __bf16 bf16x8;
typedef __attribute__((ext_vector_type(4))) float f32x4;

static __device__ __forceinline__ unsigned short bfhi(float f) {
    __hip_bfloat16 h = __float2bfloat16(f);
    return *reinterpret_cast<unsigned short*>(&h);
}
static __device__ __forceinline__ float bf2f(unsigned short u) {
    unsigned v = (unsigned)u << 16;
    return __uint_as_float(v);
}
static __device__ __forceinline__ bf16x8 ldfrag(const void* p) {
    bf16x8 r;
    __builtin_memcpy(&r, p, 16);
    return r;
}
// LDS frag-bank swizzle: XOR bits>=4 only (8B writes / 16B reads stay aligned).
static __device__ __forceinline__ int swz(int a) {
    return a ^ (((a >> 8) & 3) << 5) ^ (((a >> 12) & 3) << 4);
}

// Fragment addressing (mfma_f32_16x16x32_bf16):
//  A: lane l holds A[R0 + (l&15)][32*ks + 8*(l>>4) + j], j=0..7
//  B: lane l holds B[32*ks + 8*(l>>4) + j][C0 + (l&15)]
//  C/D: col = C0 + (lane&15), row = R0 + (lane>>4)*4 + reg   [verified layout]
// LDS frag order: byte = swz( (((slot*64 + lane)*8 + j) * 2) ), slot = ks*4 + rb/cb.
// B-fragments live in VGPRs; LDS buffer reused for activation staging.

// ============ fused: direct ELL build (blocks 0..BB-1) || input GEMM (rest) ============
// ELL build: 1 pass, global atomic per edge. No bucket, no sentinel init (gather
// selects invalid slots to the zero row at index NN).
#define BB 384
#define GB 256
__global__ void __launch_bounds__(512) k_front(const int* __restrict__ src,
                                               const int* __restrict__ dst,
                                               int* __restrict__ cnt,
                                               int* __restrict__ ell,
                                               const float* __restrict__ x,
                                               const float* __restrict__ W0,
                                               const float* __restrict__ b0,
                                               float* __restrict__ h) {
    __shared__ unsigned short sS[2 * 8192];   // 2 planes x 16 KB (W0 prepack, then x tiles)
    if (blockIdx.x < BB) {
        // ---- direct ELL build: p = atomicAdd(cnt[dst]); ell[dst*64+p] = src ----
        const int T = BB * 512;
        int e = blockIdx.x * 512 + (int)threadIdx.x;
        for (; e + 3 * T < NE; e += 4 * T) {
            int d0 = dst[e];         int s0 = src[e];
            int d1 = dst[e + T];     int s1 = src[e + T];
            int d2 = dst[e + 2 * T]; int s2 = src[e + 2 * T];
            int d3 = dst[e + 3 * T]; int s3 = src[e + 3 * T];
            int p0 = atomicAdd(&cnt[d0], 1);
            int p1 = atomicAdd(&cnt[d1], 1);
            int p2 = atomicAdd(&cnt[d2], 1);
            int p3 = atomicAdd(&cnt[d3], 1);
            if (p0 < MAXD) ell[((size_t)d0 << 6) + p0] = s0;
            if (p1 < MAXD) ell[((size_t)d1 << 6) + p1] = s1;
            if (p2 < MAXD) ell[((size_t)d2 << 6) + p2] = s2;
            if (p3 < MAXD) ell[((size_t)d3 << 6) + p3] = s3;
        }
        for (; e < NE; e += T) {
            int d = dst[e]; int s = src[e];
            int p = atomicAdd(&cnt[d], 1);
            if (p < MAXD) ell[((size_t)d << 6) + p] = s;
        }
    } else {
        // ---- input GEMM via MFMA bf16x3: h = relu(x @ W0 + b0) ----
        unsigned short* sP0 = sS;            // hi plane
        unsigned short* sP1 = sS + 8192;     // lo plane
        // prepack W0 into fragment order (transient)
        for (int i = threadIdx.x; i < 8192; i += 512) {
            int k = i >> 6, c = i & 63;
            int slot = ((k >> 5) << 2) | (c >> 4);
            int ln   = (((k >> 3) & 3) << 4) | (c & 15);
            int ba   = swz((((((slot << 6) | ln) << 3) | (k & 7)) << 1));
            float w0 = W0[i];
            unsigned short hh = bfhi(w0);
            *(unsigned short*)((char*)sP0 + ba) = hh;
            *(unsigned short*)((char*)sP1 + ba) = bfhi(w0 - bf2f(hh));
        }
        __syncthreads();
        int lane = threadIdx.x & 63;
        int wv   = threadIdx.x >> 6;          // 8 waves
        int cb   = wv & 3;                    // 16-col block
        int rbh  = wv >> 2;                   // row half: rb in {2*rbh, 2*rbh+1}
        int col  = (cb << 4) | (lane & 15);
        float bj = b0[col];
        int r0   = (lane >> 4) << 2;
        bf16x8 Bh[4], Bl[4];                  // register-resident W0 fragments
#pragma unroll
        for (int ks = 0; ks < 4; ++ks) {
            int bb = swz(((((ks << 2) | cb) << 6) | lane) << 4);
            Bh[ks] = ldfrag((const char*)sP0 + bb);
            Bl[ks] = ldfrag((const char*)sP1 + bb);
        }
        for (int t = blockIdx.x - BB; t < NTILE; t += GB) {
            int n0 = t << 6;
            __syncthreads();                  // sS free (covers B-frag reads, 1st iter)
#pragma unroll
            for (int i = 0; i < 4; ++i) {     // stage 64x128 x-tile -> hi/lo frags
                int tau = (int)threadIdx.x + (i << 9);
                int r = tau >> 5, kq = tau & 31;
                int n = n0 + r;
                float4 v = make_float4(0.f, 0.f, 0.f, 0.f);
                if (n < NN) v = *(const float4*)(x + ((size_t)n << 7) + (kq << 2));
                int k0   = kq << 2;
                int slot = ((k0 >> 5) << 2) | (r >> 4);
                int ln   = (((k0 >> 3) & 3) << 4) | (r & 15);
                int ba   = swz((((((slot << 6) | ln) << 3) | (k0 & 7)) << 1));
                unsigned short h0 = bfhi(v.x), h1 = bfhi(v.y),
                               h2 = bfhi(v.z), h3 = bfhi(v.w);
                *(ushort4*)((char*)sP0 + ba) = make_ushort4(h0, h1, h2, h3);
                *(ushort4*)((char*)sP1 + ba) = make_ushort4(
                    bfhi(v.x - bf2f(h0)), bfhi(v.y - bf2f(h1)),
                    bfhi(v.z - bf2f(h2)), bfhi(v.w - bf2f(h3)));
            }
            __syncthreads();
            f32x4 acc[2] = {{0.f,0.f,0.f,0.f},{0.f,0.f,0.f,0.f}};
#pragma unroll
            for (int ks = 0; ks < 4; ++ks) {
#pragma unroll
                for (int rl = 0; rl < 2; ++rl) {
                    int rb = (rbh << 1) | rl;
                    int ab = swz(((((ks << 2) | rb) << 6) | lane) << 4);
                    bf16x8 ah = ldfrag((const char*)sP0 + ab);
                    bf16x8 al = ldfrag((const char*)sP1 + ab);
                    acc[rl] = __builtin_amdgcn_mfma_f32_16x16x32_bf16(ah, Bh[ks], acc[rl], 0, 0, 0);
                    acc[rl] = __builtin_amdgcn_mfma_f32_16x16x32_bf16(ah, Bl[ks], acc[rl], 0, 0, 0);
                    acc[rl] = __builtin_amdgcn_mfma_f32_16x16x32_bf16(al, Bh[ks], acc[rl], 0, 0, 0);
                }
            }
#pragma unroll
            for (int rl = 0; rl < 2; ++rl) {
                int rb = (rbh << 1) | rl;
#pragma unroll
                for (int reg = 0; reg < 4; ++reg) {
                    int row = (rb << 4) + r0 + reg;
                    int n = n0 + row;
                    if (n < NN)
                        h[((size_t)n << 6) + col] = fmaxf(acc[rl][reg] + bj, 0.f);
                }
            }
        }
    }
}

// ---- gemmLR via MFMA bf16x3: g(bf16) = h@Wl ; r(fp32,in-place) = h@Wr + bl ----
// Wl/Wr fragments register-resident; sS (16 KB) = transient W prepack, then h-tile staging.
__device__ __forceinline__ void gemmLR_mfma(unsigned short* sS,
                                            int tid, int nblk, int bidx,
                                            float* __restrict__ h_r,
                                            __hip_bfloat16* __restrict__ g,
                                            const float* __restrict__ Wl,
                                            const float* __restrict__ bl,
                                            const float* __restrict__ Wr) {
    unsigned short* sP0 = sS;            // hi plane (8 KB)
    unsigned short* sP1 = sS + 4096;     // lo plane
    int lane = tid & 63;
    int cb   = tid >> 6;                 // 4 waves = 4 col-blocks
    bf16x8 BLh[2], BLl[2], BRh[2], BRl[2];
    // prepack Wl -> frags -> regs
    for (int i = tid; i < 4096; i += 256) {
        int k = i >> 6, c = i & 63;
        int slot = ((k >> 5) << 2) | (c >> 4);
        int ln   = (((k >> 3) & 3) << 4) | (c & 15);
        int ba   = swz((((((slot << 6) | ln) << 3) | (k & 7)) << 1));
        float w = Wl[i];
        unsigned short hh = bfhi(w);
        *(unsigned short*)((char*)sP0 + ba) = hh;
        *(unsigned short*)((char*)sP1 + ba) = bfhi(w - bf2f(hh));
    }
    __syncthreads();
#pragma unroll
    for (int ks = 0; ks < 2; ++ks) {
        int bb = swz(((((ks << 2) | cb) << 6) | lane) << 4);
        BLh[ks] = ldfrag((const char*)sP0 + bb);
        BLl[ks] = ldfrag((const char*)sP1 + bb);
    }
    __syncthreads();
    // prepack Wr -> frags -> regs
    for (int i = tid; i < 4096; i += 256) {
        int k = i >> 6, c = i & 63;
        int slot = ((k >> 5) << 2) | (c >> 4);
        int ln   = (((k >> 3) & 3) << 4) | (c & 15);
        int ba   = swz((((((slot << 6) | ln) << 3) | (k & 7)) << 1));
        float w = Wr[i];
        unsigned short hh = bfhi(w);
        *(unsigned short*)((char*)sP0 + ba) = hh;
        *(unsigned short*)((char*)sP1 + ba) = bfhi(w - bf2f(hh));
    }
    __syncthreads();
#pragma unroll
    for (int ks = 0; ks < 2; ++ks) {
        int bb = swz(((((ks << 2) | cb) << 6) | lane) << 4);
        BRh[ks] = ldfrag((const char*)sP0 + bb);
        BRl[ks] = ldfrag((const char*)sP1 + bb);
    }
    int col = (cb << 4) | (lane & 15);
    float bj = bl[col];
    int r0  = (lane >> 4) << 2;
    unsigned short* gp = (unsigned short*)g;
    for (int t = bidx; t < NTILE; t += nblk) {
        int n0 = t << 6;
        __syncthreads();                     // sS free (covers B-frag reads, 1st iter)
#pragma unroll
        for (int i = 0; i < 4; ++i) {        // stage 64x64 h-tile -> hi/lo frags
            int tau = tid + (i << 8);
            int r = tau >> 4, kq = tau & 15;
            int n = n0 + r;
            float4 v = make_float4(0.f, 0.f, 0.f, 0.f);
            if (n < NN) v = *(const float4*)(h_r + ((size_t)n << 6) + (kq << 2));
            int k0   = kq << 2;
            int slot = ((k0 >> 5) << 2) | (r >> 4);
            int ln   = (((k0 >> 3) & 3) << 4) | (r & 15);
            int ba   = swz((((((slot << 6) | ln) << 3) | (k0 & 7)) << 1));
            unsigned short h0 = bfhi(v.x), h1 = bfhi(v.y),
                           h2 = bfhi(v.z), h3 = bfhi(v.w);
            *(ushort4*)((char*)sP0 + ba) = make_ushort4(h0, h1, h2, h3);
            *(ushort4*)((char*)sP1 + ba) = make_ushort4(
                bfhi(v.x - bf2f(h0)), bfhi(v.y - bf2f(h1)),
                bfhi(v.z - bf2f(h2)), bfhi(v.w - bf2f(h3)));
        }
        __syncthreads();
        f32x4 accl[4] = {{0.f,0.f,0.f,0.f},{0.f,0.f,0.f,0.f},
                         {0.f,0.f,0.f,0.f},{0.f,0.f,0.f,0.f}};
        f32x4 accr[4] = {{0.f,0.f,0.f,0.f},{0.f,0.f,0.f,0.f},
                         {0.f,0.f,0.f,0.f},{0.f,0.f,0.f,0.f}};
#pragma unroll
        for (int ks = 0; ks < 2; ++ks) {
#pragma unroll
            for (int rb = 0; rb < 4; ++rb) {
                int ab = swz(((((ks << 2) | rb) << 6) | lane) << 4);
                bf16x8 ah = ldfrag((const char*)sP0 + ab);
                bf16x8 al = ldfrag((const char*)sP1 + ab);
                accl[rb] = __builtin_amdgcn_mfma_f32_16x16x32_bf16(ah, BLh[ks], accl[rb], 0, 0, 0);
                accl[rb] = __builtin_amdgcn_mfma_f32_16x16x32_bf16(ah, BLl[ks], accl[rb], 0, 0, 0);
                accl[rb] = __builtin_amdgcn_mfma_f32_16x16x32_bf16(al, BLh[ks], accl[rb], 0, 0, 0);
                accr[rb] = __builtin_amdgcn_mfma_f32_16x16x32_bf16(ah, BRh[ks], accr[rb], 0, 0, 0);
                accr[rb] = __builtin_amdgcn_mfma_f32_16x16x32_bf16(ah, BRl[ks], accr[rb], 0, 0, 0);
                accr[rb] = __builtin_amdgcn_mfma_f32_16x16x32_bf16(al, BRh[ks], accr[rb], 0, 0, 0);
            }
        }
#pragma unroll
        for (int rb = 0; rb < 4; ++rb) {
#pragma unroll
            for (int reg = 0; reg < 4; ++reg) {
                int row = (rb << 4) + r0 + reg;
                int n = n0 + row;
                if (n < NN) {
                    size_t o = ((size_t)n << 6) + col;
                    gp[o]  = bfhi(accl[rb][reg]);
                    h_r[o] = accr[rb][reg] + bj;
                }
            }
        }
    }
}

// ============ standalone gemmLR (layers 0,1,2) ============
__global__ void __launch_bounds__(256) k_gemmLR(float* __restrict__ h_r,
                                                __hip_bfloat16* __restrict__ g,
                                                const float* __restrict__ Wl,
                                                const float* __restrict__ bl,
                                                const float* __restrict__ Wr) {
    __shared__ unsigned short sS[2 * 4096];
    gemmLR_mfma(sS, threadIdx.x, gridDim.x, blockIdx.x, h_r, g, Wl, bl, Wr);
}

// ============ gather: 8 nodes/wave, 16 B/lane (uint4 = 8 bf16), 8 edges/load-instr.
// Invalid slots (>= deg, incl. uninitialized ELL tails) selected to the zero row at
// index NN -> L1-resident, padding costs ~nothing. No sentinel init needed. ========
#define ACCU(U) { \
    a0 += __uint_as_float((U).x << 16); a1 += __uint_as_float((U).x & 0xffff0000u); \
    a2 += __uint_as_float((U).y << 16); a3 += __uint_as_float((U).y & 0xffff0000u); \
    a4 += __uint_as_float((U).z << 16); a5 += __uint_as_float((U).z & 0xffff0000u); \
    a6 += __uint_as_float((U).w << 16); a7 += __uint_as_float((U).w & 0xffff0000u); }
__global__ void __launch_bounds__(256) k_gather(const uint4* __restrict__ g4,
                                                float* __restrict__ r_h,
                                                const int* __restrict__ cnt,
                                                const int* __restrict__ ell) {
    int lane = threadIdx.x & 63;
    int o    = lane >> 3;                   // node slot (8 per wave)
    int c8   = lane & 7;                    // 8 lanes x 16B cover one 128B G row
    int wv = __builtin_amdgcn_readfirstlane((int)((blockIdx.x * 256 + threadIdx.x) >> 6));
    int nw = (gridDim.x * 256) >> 6;
    for (int p = wv; p < NN / 8; p += nw) {
        int myn = 8 * p + o;
        int d   = cnt[myn];
        int dc  = min(d, MAXD);
        int dm  = max(dc, __shfl_xor(dc, 8));
        dm      = max(dm, __shfl_xor(dm, 16));
        dm      = max(dm, __shfl_xor(dm, 32));
        int iters = (dm + 7) & ~7;              // wave-max, rounded to 8
        // lane c8 holds ELL slots 8*c8 .. 8*c8+7 of its node
        const int* er = ell + ((size_t)myn << 6) + (c8 << 3);
        int4 l0 = *(const int4*)er;
        int4 l1 = *(const int4*)(er + 4);
        float a0=0.f,a1=0.f,a2=0.f,a3=0.f,a4=0.f,a5=0.f,a6=0.f,a7=0.f;
        for (int j0 = 0; j0 < iters; j0 += 8) {
            int sl = (o << 3) | (j0 >> 3);
            int i0 = __shfl(l0.x, sl);
            int i1 = __shfl(l0.y, sl);
            int i2 = __shfl(l0.z, sl);
            int i3 = __shfl(l0.w, sl);
            int i4 = __shfl(l1.x, sl);
            int i5 = __shfl(l1.y, sl);
            int i6 = __shfl(l1.z, sl);
            int i7 = __shfl(l1.w, sl);
            i0 = (j0 + 0 < d) ? i0 : NN;
            i1 = (j0 + 1 < d) ? i1 : NN;
            i2 = (j0 + 2 < d) ? i2 : NN;
            i3 = (j0 + 3 < d) ? i3 : NN;
            i4 = (j0 + 4 < d) ? i4 : NN;
            i5 = (j0 + 5 < d) ? i5 : NN;
            i6 = (j0 + 6 < d) ? i6 : NN;
            i7 = (j0 + 7 < d) ? i7 : NN;
            uint4 u0 = g4[(size_t)i0 * 8 + c8];
            uint4 u1 = g4[(size_t)i1 * 8 + c8];
            uint4 u2 = g4[(size_t)i2 * 8 + c8];
            uint4 u3 = g4[(size_t)i3 * 8 + c8];
            uint4 u4 = g4[(size_t)i4 * 8 + c8];
            uint4 u5 = g4[(size_t)i5 * 8 + c8];
            uint4 u6 = g4[(size_t)i6 * 8 + c8];
            uint4 u7 = g4[(size_t)i7 * 8 + c8];
            ACCU(u0); ACCU(u1); ACCU(u2); ACCU(u3);
            ACCU(u4); ACCU(u5); ACCU(u6); ACCU(u7);
        }
        float inv = 1.0f / fmaxf((float)d, 1.0f);
        float4* rp = (float4*)(r_h + ((size_t)myn << 6) + (c8 << 3));
        float4 rv0 = rp[0], rv1 = rp[1];
        rv0.x = fmaxf(fmaf(a0, inv, rv0.x), 0.0f);
        rv0.y = fmaxf(fmaf(a1, inv, rv0.y), 0.0f);
        rv0.z = fmaxf(fmaf(a2, inv, rv0.z), 0.0f);
        rv0.w = fmaxf(fmaf(a3, inv, rv0.w), 0.0f);
        rv1.x = fmaxf(fmaf(a4, inv, rv1.x), 0.0f);
        rv1.y = fmaxf(fmaf(a5, inv, rv1.y), 0.0f);
        rv1.z = fmaxf(fmaf(a6, inv, rv1.z), 0.0f);
        rv1.w = fmaxf(fmaf(a7, inv, rv1.w), 0.0f);
        rp[0] = rv0; rp[1] = rv1;
    }
}

// ============ pooling (batch sorted -> run accumulate) ============
__global__ void __launch_bounds__(256) k_pool(const int* __restrict__ batch,
                                              const float* __restrict__ h,
                                              float* __restrict__ pool,
                                              float* __restrict__ cntg) {
    int lane = threadIdx.x & 63;
    int wid  = (blockIdx.x * 256 + threadIdx.x) >> 6;
    int nw   = (gridDim.x * 256) >> 6;
    int chunk = (NN + nw - 1) / nw;
    int n0 = wid * chunk;
    if (n0 >= NN) return;
    int n1 = min(n0 + chunk, NN);
    int cur = batch[n0];
    float acc = 0.0f, acc_c = 0.0f;
    for (int n = n0; n < n1; ++n) {
        int b = batch[n];
        if (b != cur) {
            atomicAdd(&pool[(size_t)cur * 64 + lane], acc);
            if (lane == 0) atomicAdd(&cntg[cur], acc_c);
            acc = 0.0f; acc_c = 0.0f; cur = b;
        }
        acc   += h[(size_t)n * 64 + lane];
        acc_c += 1.0f;
    }
    atomicAdd(&pool[(size_t)cur * 64 + lane], acc);
    if (lane == 0) atomicAdd(&cntg[cur], acc_c);
}

// ============ output GEMM ============
__global__ void __launch_bounds__(256) k_out(const float* __restrict__ pool,
                                             const float* __restrict__ cntg,
                                             const float* __restrict__ W1,
                                             const float* __restrict__ b1,
                                             float* __restrict__ out) {
    __shared__ float sW[64 * 64];
    for (int i = threadIdx.x; i < 64 * 64; i += 256) sW[i] = W1[i];
    __syncthreads();
    int lane = threadIdx.x & 63;
    int wid  = (blockIdx.x * 256 + threadIdx.x) >> 6;
    int nw   = (gridDim.x * 256) >> 6;
    for (int gidx = wid; gidx < NG; gidx += nw) {
        float ic = 1.0f / fmaxf(cntg[gidx], 1.0f);
        float acc = 0.0f;
#pragma unroll
        for (int k = 0; k < 64; ++k)
            acc = fmaf(pool[(size_t)gidx * 64 + k], sW[k * 64 + lane], acc);
        out[(size_t)gidx * 64 + lane] = fmaf(acc, ic, b1[lane]);
    }
}

extern "C" void kernel_launch(void* const* d_in, const int* in_sizes, int n_in,
                              void* d_out, int out_size, void* d_ws, size_t ws_size,
                              hipStream_t stream) {
    const float* x     = (const float*)d_in[0];
    const int*   ei    = (const int*)d_in[1];   // [2,E]
    const int*   batch = (const int*)d_in[3];
    const float* W0    = (const float*)d_in[4];
    const float* b0    = (const float*)d_in[5];
    const float* Wl    = (const float*)d_in[6];
    const float* bl    = (const float*)d_in[7];
    const float* Wr    = (const float*)d_in[8];
    const float* W1    = (const float*)d_in[9];
    const float* b1    = (const float*)d_in[10];
    float* out = (float*)d_out;

    char* ws = (char*)d_ws;
    size_t off = 0;
    auto alloc = [&](size_t bytes) -> void* {
        void* p = ws + off;
        off += (bytes + 255) & ~(size_t)255;
        return p;
    };
    float*          A      = (float*)alloc((size_t)NN * 64 * 4);          // h / r / h'
    __hip_bfloat16* G      = (__hip_bfloat16*)alloc((size_t)NN * 64 * 2); // g (bf16), NN rows
    // zero region starts EXACTLY at G's row NN (sentinel zero row), then cnt/pool/cntg
    size_t zstart = off;
    (void)alloc((size_t)MAXD * 2);                                        // G zero row (128 B)
    int*   cnt    = (int*)alloc((size_t)NN * 4);                          // atomic counters
    float* pool   = (float*)alloc((size_t)NG * 64 * 4);
    float* cntg   = (float*)alloc((size_t)NG * 4);
    size_t zlen = off - zstart;
    int*   ell    = (int*)alloc((size_t)NN * MAXD * 4);                   // ELL (tails garbage, masked)

    const int* src = ei;
    const int* dst = ei + NE;

    hipMemsetAsync(ws + zstart, 0, zlen, stream);

    // direct ELL build || input projection (MFMA)
    k_front<<<BB + GB, 512, 0, stream>>>(src, dst, cnt, ell, x, W0, b0, A);

    for (int l = 0; l < 3; ++l) {
        k_gemmLR<<<512, 256, 0, stream>>>(A, G,
                                          Wl + (size_t)l * 64 * 64,
                                          bl + (size_t)l * 64,
                                          Wr + (size_t)l * 64 * 64);
        k_gather<<<3125, 256, 0, stream>>>((const uint4*)G, A, cnt, ell);
    }

    k_pool<<<256, 256, 0, stream>>>(batch, A, pool, cntg);
    k_out<<<128, 256, 0, stream>>>(pool, cntg, W1, b1, out);
}

// Round 7
// 377.664 us; speedup vs baseline: 1.2887x; 1.2887x over previous
//
#include <hip/hip_runtime.h>
#include <hip/hip_bf16.h>

#define NN 100000
#define NE 1600000
#define DIN 128
#define NG 512
#define MAXD 64
#define NBUK 391               // dst>>8 buckets (256 nodes each)
#define BCAP 5120              // mean 4092, +16 sigma
#define CHUNK ((NE + NBUK - 1) / NBUK)
#define NTILE ((NN + 63) >> 6)  // 64-node tiles

typedef __attribute__((ext_vector_type(8))) __bf16 bf16x8;
typedef __attribute__((ext_vector_type(4))) float f32x4;

static __device__ __forceinline__ unsigned short bfhi(float f) {
    __hip_bfloat16 h = __float2bfloat16(f);
    return *reinterpret_cast<unsigned short*>(&h);
}
static __device__ __forceinline__ float bf2f(unsigned short u) {
    unsigned v = (unsigned)u << 16;
    return __uint_as_float(v);
}
static __device__ __forceinline__ bf16x8 ldfrag(const void* p) {
    bf16x8 r;
    __builtin_memcpy(&r, p, 16);
    return r;
}
// LDS frag-bank swizzle: XOR bits>=4 only (8B writes / 16B reads stay aligned).
static __device__ __forceinline__ int swz(int a) {
    return a ^ (((a >> 8) & 3) << 5) ^ (((a >> 12) & 3) << 4);
}

// Fragment addressing (mfma_f32_16x16x32_bf16):
//  A: lane l holds A[R0 + (l&15)][32*ks + 8*(l>>4) + j], j=0..7
//  B: lane l holds B[32*ks + 8*(l>>4) + j][C0 + (l&15)]
//  C/D: col = C0 + (lane&15), row = R0 + (lane>>4)*4 + reg   [verified layout]
// LDS frag order: byte = swz( (((slot*64 + lane)*8 + j) * 2) ), slot = ks*4 + rb/cb.

// ============ fused: phase-1 binning (blocks 0..NBUK) || input GEMM (rest) ============
// (round-5 proven structure: LDS histogram + 1 global atomic per block-bucket)
#define GB 256
__global__ void __launch_bounds__(512) k_front(const int* __restrict__ src,
                                               const int* __restrict__ dst,
                                               int* __restrict__ cursor,
                                               unsigned int* __restrict__ bucket,
                                               const float* __restrict__ x,
                                               const float* __restrict__ W0,
                                               const float* __restrict__ b0,
                                               float* __restrict__ h) {
    __shared__ unsigned short sS[2 * 8192];   // 2 planes x 16 KB (W0 prepack, then x tiles)
    __shared__ int lcnt[NBUK];
    __shared__ int lbase[NBUK];
    if (blockIdx.x < NBUK) {
        for (int i = threadIdx.x; i < NBUK; i += 512) lcnt[i] = 0;
        __syncthreads();
        int e0 = blockIdx.x * CHUNK;
        int e1 = min(e0 + CHUNK, NE);
        for (int e = e0 + (int)threadIdx.x; e < e1; e += 512)
            atomicAdd(&lcnt[dst[e] >> 8], 1);
        __syncthreads();
        for (int i = threadIdx.x; i < NBUK; i += 512) {
            int c = lcnt[i];
            lbase[i] = c ? atomicAdd(&cursor[i], c) : 0;
            lcnt[i] = 0;
        }
        __syncthreads();
        for (int e = e0 + (int)threadIdx.x; e < e1; e += 512) {
            int d = dst[e];
            int s = src[e];
            int bk = d >> 8;
            int pos = lbase[bk] + atomicAdd(&lcnt[bk], 1);
            if (pos < BCAP)
                bucket[(size_t)bk * BCAP + pos] = ((unsigned)s << 8) | (unsigned)(d & 255);
        }
    } else {
        // ---- input GEMM via MFMA bf16x3: h = relu(x @ W0 + b0) ----
        unsigned short* sP0 = sS;
        unsigned short* sP1 = sS + 8192;
        for (int i = threadIdx.x; i < 8192; i += 512) {
            int k = i >> 6, c = i & 63;
            int slot = ((k >> 5) << 2) | (c >> 4);
            int ln   = (((k >> 3) & 3) << 4) | (c & 15);
            int ba   = swz((((((slot << 6) | ln) << 3) | (k & 7)) << 1));
            float w0 = W0[i];
            unsigned short hh = bfhi(w0);
            *(unsigned short*)((char*)sP0 + ba) = hh;
            *(unsigned short*)((char*)sP1 + ba) = bfhi(w0 - bf2f(hh));
        }
        __syncthreads();
        int lane = threadIdx.x & 63;
        int wv   = threadIdx.x >> 6;
        int cb   = wv & 3;
        int rbh  = wv >> 2;
        int col  = (cb << 4) | (lane & 15);
        float bj = b0[col];
        int r0   = (lane >> 4) << 2;
        bf16x8 Bh[4], Bl[4];
#pragma unroll
        for (int ks = 0; ks < 4; ++ks) {
            int bb = swz(((((ks << 2) | cb) << 6) | lane) << 4);
            Bh[ks] = ldfrag((const char*)sP0 + bb);
            Bl[ks] = ldfrag((const char*)sP1 + bb);
        }
        for (int t = blockIdx.x - NBUK; t < NTILE; t += GB) {
            int n0 = t << 6;
            __syncthreads();
#pragma unroll
            for (int i = 0; i < 4; ++i) {
                int tau = (int)threadIdx.x + (i << 9);
                int r = tau >> 5, kq = tau & 31;
                int n = n0 + r;
                float4 v = make_float4(0.f, 0.f, 0.f, 0.f);
                if (n < NN) v = *(const float4*)(x + ((size_t)n << 7) + (kq << 2));
                int k0   = kq << 2;
                int slot = ((k0 >> 5) << 2) | (r >> 4);
                int ln   = (((k0 >> 3) & 3) << 4) | (r & 15);
                int ba   = swz((((((slot << 6) | ln) << 3) | (k0 & 7)) << 1));
                unsigned short h0 = bfhi(v.x), h1 = bfhi(v.y),
                               h2 = bfhi(v.z), h3 = bfhi(v.w);
                *(ushort4*)((char*)sP0 + ba) = make_ushort4(h0, h1, h2, h3);
                *(ushort4*)((char*)sP1 + ba) = make_ushort4(
                    bfhi(v.x - bf2f(h0)), bfhi(v.y - bf2f(h1)),
                    bfhi(v.z - bf2f(h2)), bfhi(v.w - bf2f(h3)));
            }
            __syncthreads();
            f32x4 acc[2] = {{0.f,0.f,0.f,0.f},{0.f,0.f,0.f,0.f}};
#pragma unroll
            for (int ks = 0; ks < 4; ++ks) {
#pragma unroll
                for (int rl = 0; rl < 2; ++rl) {
                    int rb = (rbh << 1) | rl;
                    int ab = swz(((((ks << 2) | rb) << 6) | lane) << 4);
                    bf16x8 ah = ldfrag((const char*)sP0 + ab);
                    bf16x8 al = ldfrag((const char*)sP1 + ab);
                    acc[rl] = __builtin_amdgcn_mfma_f32_16x16x32_bf16(ah, Bh[ks], acc[rl], 0, 0, 0);
                    acc[rl] = __builtin_amdgcn_mfma_f32_16x16x32_bf16(ah, Bl[ks], acc[rl], 0, 0, 0);
                    acc[rl] = __builtin_amdgcn_mfma_f32_16x16x32_bf16(al, Bh[ks], acc[rl], 0, 0, 0);
                }
            }
#pragma unroll
            for (int rl = 0; rl < 2; ++rl) {
                int rb = (rbh << 1) | rl;
#pragma unroll
                for (int reg = 0; reg < 4; ++reg) {
                    int row = (rb << 4) + r0 + reg;
                    int n = n0 + row;
                    if (n < NN)
                        h[((size_t)n << 6) + col] = fmaxf(acc[rl][reg] + bj, 0.f);
                }
            }
        }
    }
}

// ---- gemmLR via MFMA bf16x3 (4-wave body, used by k_mid layer 0) ----
__device__ __forceinline__ void gemmLR_mfma(unsigned short* sS,
                                            int tid, int nblk, int bidx,
                                            float* __restrict__ h_r,
                                            __hip_bfloat16* __restrict__ g,
                                            const float* __restrict__ Wl,
                                            const float* __restrict__ bl,
                                            const float* __restrict__ Wr) {
    unsigned short* sP0 = sS;
    unsigned short* sP1 = sS + 4096;
    int lane = tid & 63;
    int cb   = tid >> 6;
    bf16x8 BLh[2], BLl[2], BRh[2], BRl[2];
    for (int i = tid; i < 4096; i += 256) {
        int k = i >> 6, c = i & 63;
        int slot = ((k >> 5) << 2) | (c >> 4);
        int ln   = (((k >> 3) & 3) << 4) | (c & 15);
        int ba   = swz((((((slot << 6) | ln) << 3) | (k & 7)) << 1));
        float w = Wl[i];
        unsigned short hh = bfhi(w);
        *(unsigned short*)((char*)sP0 + ba) = hh;
        *(unsigned short*)((char*)sP1 + ba) = bfhi(w - bf2f(hh));
    }
    __syncthreads();
#pragma unroll
    for (int ks = 0; ks < 2; ++ks) {
        int bb = swz(((((ks << 2) | cb) << 6) | lane) << 4);
        BLh[ks] = ldfrag((const char*)sP0 + bb);
        BLl[ks] = ldfrag((const char*)sP1 + bb);
    }
    __syncthreads();
    for (int i = tid; i < 4096; i += 256) {
        int k = i >> 6, c = i & 63;
        int slot = ((k >> 5) << 2) | (c >> 4);
        int ln   = (((k >> 3) & 3) << 4) | (c & 15);
        int ba   = swz((((((slot << 6) | ln) << 3) | (k & 7)) << 1));
        float w = Wr[i];
        unsigned short hh = bfhi(w);
        *(unsigned short*)((char*)sP0 + ba) = hh;
        *(unsigned short*)((char*)sP1 + ba) = bfhi(w - bf2f(hh));
    }
    __syncthreads();
#pragma unroll
    for (int ks = 0; ks < 2; ++ks) {
        int bb = swz(((((ks << 2) | cb) << 6) | lane) << 4);
        BRh[ks] = ldfrag((const char*)sP0 + bb);
        BRl[ks] = ldfrag((const char*)sP1 + bb);
    }
    int col = (cb << 4) | (lane & 15);
    float bj = bl[col];
    int r0  = (lane >> 4) << 2;
    unsigned short* gp = (unsigned short*)g;
    for (int t = bidx; t < NTILE; t += nblk) {
        int n0 = t << 6;
        __syncthreads();
#pragma unroll
        for (int i = 0; i < 4; ++i) {
            int tau = tid + (i << 8);
            int r = tau >> 4, kq = tau & 15;
            int n = n0 + r;
            float4 v = make_float4(0.f, 0.f, 0.f, 0.f);
            if (n < NN) v = *(const float4*)(h_r + ((size_t)n << 6) + (kq << 2));
            int k0   = kq << 2;
            int slot = ((k0 >> 5) << 2) | (r >> 4);
            int ln   = (((k0 >> 3) & 3) << 4) | (r & 15);
            int ba   = swz((((((slot << 6) | ln) << 3) | (k0 & 7)) << 1));
            unsigned short h0 = bfhi(v.x), h1 = bfhi(v.y),
                           h2 = bfhi(v.z), h3 = bfhi(v.w);
            *(ushort4*)((char*)sP0 + ba) = make_ushort4(h0, h1, h2, h3);
            *(ushort4*)((char*)sP1 + ba) = make_ushort4(
                bfhi(v.x - bf2f(h0)), bfhi(v.y - bf2f(h1)),
                bfhi(v.z - bf2f(h2)), bfhi(v.w - bf2f(h3)));
        }
        __syncthreads();
        f32x4 accl[4] = {{0.f,0.f,0.f,0.f},{0.f,0.f,0.f,0.f},
                         {0.f,0.f,0.f,0.f},{0.f,0.f,0.f,0.f}};
        f32x4 accr[4] = {{0.f,0.f,0.f,0.f},{0.f,0.f,0.f,0.f},
                         {0.f,0.f,0.f,0.f},{0.f,0.f,0.f,0.f}};
#pragma unroll
        for (int ks = 0; ks < 2; ++ks) {
#pragma unroll
            for (int rb = 0; rb < 4; ++rb) {
                int ab = swz(((((ks << 2) | rb) << 6) | lane) << 4);
                bf16x8 ah = ldfrag((const char*)sP0 + ab);
                bf16x8 al = ldfrag((const char*)sP1 + ab);
                accl[rb] = __builtin_amdgcn_mfma_f32_16x16x32_bf16(ah, BLh[ks], accl[rb], 0, 0, 0);
                accl[rb] = __builtin_amdgcn_mfma_f32_16x16x32_bf16(ah, BLl[ks], accl[rb], 0, 0, 0);
                accl[rb] = __builtin_amdgcn_mfma_f32_16x16x32_bf16(al, BLh[ks], accl[rb], 0, 0, 0);
                accr[rb] = __builtin_amdgcn_mfma_f32_16x16x32_bf16(ah, BRh[ks], accr[rb], 0, 0, 0);
                accr[rb] = __builtin_amdgcn_mfma_f32_16x16x32_bf16(ah, BRl[ks], accr[rb], 0, 0, 0);
                accr[rb] = __builtin_amdgcn_mfma_f32_16x16x32_bf16(al, BRh[ks], accr[rb], 0, 0, 0);
            }
        }
#pragma unroll
        for (int rb = 0; rb < 4; ++rb) {
#pragma unroll
            for (int reg = 0; reg < 4; ++reg) {
                int row = (rb << 4) + r0 + reg;
                int n = n0 + row;
                if (n < NN) {
                    size_t o = ((size_t)n << 6) + col;
                    gp[o]  = bfhi(accl[rb][reg]);
                    h_r[o] = accr[rb][reg] + bj;
                }
            }
        }
    }
}

// ============ fused: phase-2 ELL build (blocks 0..NBUK, NO sentinel init) || gemmLR0 ==
#define MGB 512
__global__ void __launch_bounds__(256) k_mid(const unsigned int* __restrict__ bucket,
                                             const int* __restrict__ cursor,
                                             int* __restrict__ cnt,
                                             int* __restrict__ ell,
                                             float* __restrict__ h_r,
                                             __hip_bfloat16* __restrict__ g,
                                             const float* __restrict__ Wl,
                                             const float* __restrict__ bl,
                                             const float* __restrict__ Wr) {
    __shared__ unsigned short sS[2 * 4096];
    __shared__ int lc[256];
    if (blockIdx.x < NBUK) {
        lc[threadIdx.x] = 0;
        int b = blockIdx.x;
        __syncthreads();
        int m = min(cursor[b], BCAP);
        const unsigned int* bp = bucket + (size_t)b * BCAP;
        for (int i = threadIdx.x; i < m; i += 256) {
            unsigned v = bp[i];
            int dlo = (int)(v & 255u);
            int s   = (int)(v >> 8);
            int p   = atomicAdd(&lc[dlo], 1);
            if (p < MAXD)
                ell[(((size_t)b << 8) + dlo) * MAXD + p] = s;
        }
        __syncthreads();
        int n = (b << 8) + (int)threadIdx.x;
        if (n < NN) cnt[n] = lc[threadIdx.x];
    } else {
        gemmLR_mfma(sS, threadIdx.x, MGB, blockIdx.x - NBUK, h_r, g, Wl, bl, Wr);
    }
}

#define ACCU(U) { \
    a0 += __uint_as_float((U).x << 16); a1 += __uint_as_float((U).x & 0xffff0000u); \
    a2 += __uint_as_float((U).y << 16); a3 += __uint_as_float((U).y & 0xffff0000u); \
    a4 += __uint_as_float((U).z << 16); a5 += __uint_as_float((U).z & 0xffff0000u); \
    a6 += __uint_as_float((U).w << 16); a7 += __uint_as_float((U).w & 0xffff0000u); }

// ============ FUSED gather(l) + gemmLR(l+1): one 64-node tile per block-iteration ====
// 8 waves x 8 nodes gather -> h' staged from REGISTERS to swizzled LDS frags ->
// 8-wave MFMA gemm -> write g_{l+1}, r_{l+1}. h' never touches HBM.
#define FB 512
__global__ void __launch_bounds__(512) k_gg(const uint4* __restrict__ gin,
                                            float* __restrict__ rA,        // r_l in, r_{l+1} out (in-place per tile)
                                            unsigned short* __restrict__ gout,
                                            const int* __restrict__ cnt,
                                            const int* __restrict__ ell,
                                            const float* __restrict__ Wl,
                                            const float* __restrict__ bl,
                                            const float* __restrict__ Wr) {
    __shared__ unsigned short sS[2 * 4096];
    unsigned short* sP0 = sS;
    unsigned short* sP1 = sS + 4096;
    int tid = (int)threadIdx.x;
    int lane = tid & 63;
    int w    = tid >> 6;                 // 8 waves
    int cb   = w & 3;
    int rbh  = w >> 2;
    bf16x8 BLh[2], BLl[2], BRh[2], BRl[2];
    // prepack Wl -> regs
    for (int i = tid; i < 4096; i += 512) {
        int k = i >> 6, c = i & 63;
        int slot = ((k >> 5) << 2) | (c >> 4);
        int ln   = (((k >> 3) & 3) << 4) | (c & 15);
        int ba   = swz((((((slot << 6) | ln) << 3) | (k & 7)) << 1));
        float wv_ = Wl[i];
        unsigned short hh = bfhi(wv_);
        *(unsigned short*)((char*)sP0 + ba) = hh;
        *(unsigned short*)((char*)sP1 + ba) = bfhi(wv_ - bf2f(hh));
    }
    __syncthreads();
#pragma unroll
    for (int ks = 0; ks < 2; ++ks) {
        int bb = swz(((((ks << 2) | cb) << 6) | lane) << 4);
        BLh[ks] = ldfrag((const char*)sP0 + bb);
        BLl[ks] = ldfrag((const char*)sP1 + bb);
    }
    __syncthreads();
    // prepack Wr -> regs
    for (int i = tid; i < 4096; i += 512) {
        int k = i >> 6, c = i & 63;
        int slot = ((k >> 5) << 2) | (c >> 4);
        int ln   = (((k >> 3) & 3) << 4) | (c & 15);
        int ba   = swz((((((slot << 6) | ln) << 3) | (k & 7)) << 1));
        float wv_ = Wr[i];
        unsigned short hh = bfhi(wv_);
        *(unsigned short*)((char*)sP0 + ba) = hh;
        *(unsigned short*)((char*)sP1 + ba) = bfhi(wv_ - bf2f(hh));
    }
    __syncthreads();
#pragma unroll
    for (int ks = 0; ks < 2; ++ks) {
        int bb = swz(((((ks << 2) | cb) << 6) | lane) << 4);
        BRh[ks] = ldfrag((const char*)sP0 + bb);
        BRl[ks] = ldfrag((const char*)sP1 + bb);
    }
    int col = (cb << 4) | (lane & 15);
    float bj = bl[col];
    int r0  = (lane >> 4) << 2;
    int o   = lane >> 3;                 // node slot within wave
    int c8  = lane & 7;                  // 8 lanes x 16B per G row
    for (int t = blockIdx.x; t < NTILE; t += FB) {
        int n0t = t << 6;
        int myn = n0t + (w << 3) + o;
        // ---- gather (round-6 masked inner loop) ----
        int d = (myn < NN) ? cnt[myn] : 0;
        int dc = min(d, MAXD);
        int dm = max(dc, __shfl_xor(dc, 8));
        dm     = max(dm, __shfl_xor(dm, 16));
        dm     = max(dm, __shfl_xor(dm, 32));
        int iters = (dm + 7) & ~7;
        const int* er = ell + ((size_t)min(myn, NN - 1) << 6) + (c8 << 3);
        int4 l0 = *(const int4*)er;
        int4 l1 = *(const int4*)(er + 4);
        float a0=0.f,a1=0.f,a2=0.f,a3=0.f,a4=0.f,a5=0.f,a6=0.f,a7=0.f;
        for (int j0 = 0; j0 < iters; j0 += 8) {
            int sl = (o << 3) | (j0 >> 3);
            int i0 = __shfl(l0.x, sl);
            int i1 = __shfl(l0.y, sl);
            int i2 = __shfl(l0.z, sl);
            int i3 = __shfl(l0.w, sl);
            int i4 = __shfl(l1.x, sl);
            int i5 = __shfl(l1.y, sl);
            int i6 = __shfl(l1.z, sl);
            int i7 = __shfl(l1.w, sl);
            i0 = (j0 + 0 < d) ? i0 : NN;
            i1 = (j0 + 1 < d) ? i1 : NN;
            i2 = (j0 + 2 < d) ? i2 : NN;
            i3 = (j0 + 3 < d) ? i3 : NN;
            i4 = (j0 + 4 < d) ? i4 : NN;
            i5 = (j0 + 5 < d) ? i5 : NN;
            i6 = (j0 + 6 < d) ? i6 : NN;
            i7 = (j0 + 7 < d) ? i7 : NN;
            uint4 u0 = gin[(size_t)i0 * 8 + c8];
            uint4 u1 = gin[(size_t)i1 * 8 + c8];
            uint4 u2 = gin[(size_t)i2 * 8 + c8];
            uint4 u3 = gin[(size_t)i3 * 8 + c8];
            uint4 u4 = gin[(size_t)i4 * 8 + c8];
            uint4 u5 = gin[(size_t)i5 * 8 + c8];
            uint4 u6 = gin[(size_t)i6 * 8 + c8];
            uint4 u7 = gin[(size_t)i7 * 8 + c8];
            ACCU(u0); ACCU(u1); ACCU(u2); ACCU(u3);
            ACCU(u4); ACCU(u5); ACCU(u6); ACCU(u7);
        }
        float4 rv0 = make_float4(0.f,0.f,0.f,0.f), rv1 = rv0;
        if (myn < NN) {
            float inv = 1.0f / fmaxf((float)d, 1.0f);
            const float4* rp = (const float4*)(rA + ((size_t)myn << 6) + (c8 << 3));
            rv0 = rp[0]; rv1 = rp[1];
            rv0.x = fmaxf(fmaf(a0, inv, rv0.x), 0.0f);
            rv0.y = fmaxf(fmaf(a1, inv, rv0.y), 0.0f);
            rv0.z = fmaxf(fmaf(a2, inv, rv0.z), 0.0f);
            rv0.w = fmaxf(fmaf(a3, inv, rv0.w), 0.0f);
            rv1.x = fmaxf(fmaf(a4, inv, rv1.x), 0.0f);
            rv1.y = fmaxf(fmaf(a5, inv, rv1.y), 0.0f);
            rv1.z = fmaxf(fmaf(a6, inv, rv1.z), 0.0f);
            rv1.w = fmaxf(fmaf(a7, inv, rv1.w), 0.0f);
        }
        // ---- stage h' from registers into swizzled LDS frags ----
        __syncthreads();                 // previous tile's MFMA reads done
        {
            int rr = (w << 3) + o;
#pragma unroll
            for (int half = 0; half < 2; ++half) {
                float4 v = half ? rv1 : rv0;
                int k0 = (c8 << 3) + (half << 2);
                int slot = ((k0 >> 5) << 2) | (rr >> 4);
                int ln   = (((k0 >> 3) & 3) << 4) | (rr & 15);
                int ba   = swz((((((slot << 6) | ln) << 3) | (k0 & 7)) << 1));
                unsigned short h0 = bfhi(v.x), h1 = bfhi(v.y),
                               h2 = bfhi(v.z), h3 = bfhi(v.w);
                *(ushort4*)((char*)sP0 + ba) = make_ushort4(h0, h1, h2, h3);
                *(ushort4*)((char*)sP1 + ba) = make_ushort4(
                    bfhi(v.x - bf2f(h0)), bfhi(v.y - bf2f(h1)),
                    bfhi(v.z - bf2f(h2)), bfhi(v.w - bf2f(h3)));
            }
        }
        __syncthreads();
        // ---- gemmLR (8-wave split: cb x rbh) ----
        f32x4 accl[2] = {{0.f,0.f,0.f,0.f},{0.f,0.f,0.f,0.f}};
        f32x4 accr[2] = {{0.f,0.f,0.f,0.f},{0.f,0.f,0.f,0.f}};
#pragma unroll
        for (int ks = 0; ks < 2; ++ks) {
#pragma unroll
            for (int rl = 0; rl < 2; ++rl) {
                int rb = (rbh << 1) | rl;
                int ab = swz(((((ks << 2) | rb) << 6) | lane) << 4);
                bf16x8 ah = ldfrag((const char*)sP0 + ab);
                bf16x8 al = ldfrag((const char*)sP1 + ab);
                accl[rl] = __builtin_amdgcn_mfma_f32_16x16x32_bf16(ah, BLh[ks], accl[rl], 0, 0, 0);
                accl[rl] = __builtin_amdgcn_mfma_f32_16x16x32_bf16(ah, BLl[ks], accl[rl], 0, 0, 0);
                accl[rl] = __builtin_amdgcn_mfma_f32_16x16x32_bf16(al, BLh[ks], accl[rl], 0, 0, 0);
                accr[rl] = __builtin_amdgcn_mfma_f32_16x16x32_bf16(ah, BRh[ks], accr[rl], 0, 0, 0);
                accr[rl] = __builtin_amdgcn_mfma_f32_16x16x32_bf16(ah, BRl[ks], accr[rl], 0, 0, 0);
                accr[rl] = __builtin_amdgcn_mfma_f32_16x16x32_bf16(al, BRh[ks], accr[rl], 0, 0, 0);
            }
        }
#pragma unroll
        for (int rl = 0; rl < 2; ++rl) {
            int rb = (rbh << 1) | rl;
#pragma unroll
            for (int reg = 0; reg < 4; ++reg) {
                int row = (rb << 4) + r0 + reg;
                int n = n0t + row;
                if (n < NN) {
                    size_t off = ((size_t)n << 6) + col;
                    gout[off] = bfhi(accl[rl][reg]);
                    rA[off]   = accr[rl][reg] + bj;
                }
            }
        }
    }
}

// ============ final gather (layer 2): round-6 masked standalone ============
__global__ void __launch_bounds__(256) k_gather(const uint4* __restrict__ g4,
                                                float* __restrict__ r_h,
                                                const int* __restrict__ cnt,
                                                const int* __restrict__ ell) {
    int lane = threadIdx.x & 63;
    int o    = lane >> 3;
    int c8   = lane & 7;
    int wv = __builtin_amdgcn_readfirstlane((int)((blockIdx.x * 256 + threadIdx.x) >> 6));
    int nw = (gridDim.x * 256) >> 6;
    for (int p = wv; p < NN / 8; p += nw) {
        int myn = 8 * p + o;
        int d   = cnt[myn];
        int dc  = min(d, MAXD);
        int dm  = max(dc, __shfl_xor(dc, 8));
        dm      = max(dm, __shfl_xor(dm, 16));
        dm      = max(dm, __shfl_xor(dm, 32));
        int iters = (dm + 7) & ~7;
        const int* er = ell + ((size_t)myn << 6) + (c8 << 3);
        int4 l0 = *(const int4*)er;
        int4 l1 = *(const int4*)(er + 4);
        float a0=0.f,a1=0.f,a2=0.f,a3=0.f,a4=0.f,a5=0.f,a6=0.f,a7=0.f;
        for (int j0 = 0; j0 < iters; j0 += 8) {
            int sl = (o << 3) | (j0 >> 3);
            int i0 = __shfl(l0.x, sl);
            int i1 = __shfl(l0.y, sl);
            int i2 = __shfl(l0.z, sl);
            int i3 = __shfl(l0.w, sl);
            int i4 = __shfl(l1.x, sl);
            int i5 = __shfl(l1.y, sl);
            int i6 = __shfl(l1.z, sl);
            int i7 = __shfl(l1.w, sl);
            i0 = (j0 + 0 < d) ? i0 : NN;
            i1 = (j0 + 1 < d) ? i1 : NN;
            i2 = (j0 + 2 < d) ? i2 : NN;
            i3 = (j0 + 3 < d) ? i3 : NN;
            i4 = (j0 + 4 < d) ? i4 : NN;
            i5 = (j0 + 5 < d) ? i5 : NN;
            i6 = (j0 + 6 < d) ? i6 : NN;
            i7 = (j0 + 7 < d) ? i7 : NN;
            uint4 u0 = g4[(size_t)i0 * 8 + c8];
            uint4 u1 = g4[(size_t)i1 * 8 + c8];
            uint4 u2 = g4[(size_t)i2 * 8 + c8];
            uint4 u3 = g4[(size_t)i3 * 8 + c8];
            uint4 u4 = g4[(size_t)i4 * 8 + c8];
            uint4 u5 = g4[(size_t)i5 * 8 + c8];
            uint4 u6 = g4[(size_t)i6 * 8 + c8];
            uint4 u7 = g4[(size_t)i7 * 8 + c8];
            ACCU(u0); ACCU(u1); ACCU(u2); ACCU(u3);
            ACCU(u4); ACCU(u5); ACCU(u6); ACCU(u7);
        }
        float inv = 1.0f / fmaxf((float)d, 1.0f);
        float4* rp = (float4*)(r_h + ((size_t)myn << 6) + (c8 << 3));
        float4 rv0 = rp[0], rv1 = rp[1];
        rv0.x = fmaxf(fmaf(a0, inv, rv0.x), 0.0f);
        rv0.y = fmaxf(fmaf(a1, inv, rv0.y), 0.0f);
        rv0.z = fmaxf(fmaf(a2, inv, rv0.z), 0.0f);
        rv0.w = fmaxf(fmaf(a3, inv, rv0.w), 0.0f);
        rv1.x = fmaxf(fmaf(a4, inv, rv1.x), 0.0f);
        rv1.y = fmaxf(fmaf(a5, inv, rv1.y), 0.0f);
        rv1.z = fmaxf(fmaf(a6, inv, rv1.z), 0.0f);
        rv1.w = fmaxf(fmaf(a7, inv, rv1.w), 0.0f);
        rp[0] = rv0; rp[1] = rv1;
    }
}

// ============ pooling (batch sorted -> run accumulate) ============
__global__ void __launch_bounds__(256) k_pool(const int* __restrict__ batch,
                                              const float* __restrict__ h,
                                              float* __restrict__ pool,
                                              float* __restrict__ cntg) {
    int lane = threadIdx.x & 63;
    int wid  = (blockIdx.x * 256 + threadIdx.x) >> 6;
    int nw   = (gridDim.x * 256) >> 6;
    int chunk = (NN + nw - 1) / nw;
    int n0 = wid * chunk;
    if (n0 >= NN) return;
    int n1 = min(n0 + chunk, NN);
    int cur = batch[n0];
    float acc = 0.0f, acc_c = 0.0f;
    for (int n = n0; n < n1; ++n) {
        int b = batch[n];
        if (b != cur) {
            atomicAdd(&pool[(size_t)cur * 64 + lane], acc);
            if (lane == 0) atomicAdd(&cntg[cur], acc_c);
            acc = 0.0f; acc_c = 0.0f; cur = b;
        }
        acc   += h[(size_t)n * 64 + lane];
        acc_c += 1.0f;
    }
    atomicAdd(&pool[(size_t)cur * 64 + lane], acc);
    if (lane == 0) atomicAdd(&cntg[cur], acc_c);
}

// ============ output GEMM ============
__global__ void __launch_bounds__(256) k_out(const float* __restrict__ pool,
                                             const float* __restrict__ cntg,
                                             const float* __restrict__ W1,
                                             const float* __restrict__ b1,
                                             float* __restrict__ out) {
    __shared__ float sW[64 * 64];
    for (int i = threadIdx.x; i < 64 * 64; i += 256) sW[i] = W1[i];
    __syncthreads();
    int lane = threadIdx.x & 63;
    int wid  = (blockIdx.x * 256 + threadIdx.x) >> 6;
    int nw   = (gridDim.x * 256) >> 6;
    for (int gidx = wid; gidx < NG; gidx += nw) {
        float ic = 1.0f / fmaxf(cntg[gidx], 1.0f);
        float acc = 0.0f;
#pragma unroll
        for (int k = 0; k < 64; ++k)
            acc = fmaf(pool[(size_t)gidx * 64 + k], sW[k * 64 + lane], acc);
        out[(size_t)gidx * 64 + lane] = fmaf(acc, ic, b1[lane]);
    }
}

extern "C" void kernel_launch(void* const* d_in, const int* in_sizes, int n_in,
                              void* d_out, int out_size, void* d_ws, size_t ws_size,
                              hipStream_t stream) {
    const float* x     = (const float*)d_in[0];
    const int*   ei    = (const int*)d_in[1];   // [2,E]
    const int*   batch = (const int*)d_in[3];
    const float* W0    = (const float*)d_in[4];
    const float* b0    = (const float*)d_in[5];
    const float* Wl    = (const float*)d_in[6];
    const float* bl    = (const float*)d_in[7];
    const float* Wr    = (const float*)d_in[8];
    const float* W1    = (const float*)d_in[9];
    const float* b1    = (const float*)d_in[10];
    float* out = (float*)d_out;

    char* ws = (char*)d_ws;
    size_t off = 0;
    auto alloc = [&](size_t bytes) -> void* {
        void* p = ws + off;
        off += (bytes + 255) & ~(size_t)255;
        return p;
    };
    float*          A  = (float*)alloc((size_t)NN * 64 * 4);              // h / r (in-place)
    unsigned short* G0 = (unsigned short*)alloc((size_t)NN * 128);        // g ping
    size_t z1start = off;
    (void)alloc(256);                                                     // G0 zero row (row NN)
    unsigned short* G1 = (unsigned short*)alloc((size_t)NN * 128);        // g pong
    size_t z2start = off;
    (void)alloc(256);                                                     // G1 zero row (row NN)
    int*   cursor = (int*)alloc((size_t)NBUK * 4);
    float* pool   = (float*)alloc((size_t)NG * 64 * 4);
    float* cntg   = (float*)alloc((size_t)NG * 4);
    size_t z2len = off - z2start;
    int*          ell    = (int*)alloc((size_t)NN * MAXD * 4);            // ELL (tails garbage, masked)
    unsigned int* bucket = (unsigned int*)alloc((size_t)NBUK * BCAP * 4);
    int*          cnt    = (int*)alloc((size_t)NN * 4);                   // fully written by k_mid

    const int* src = ei;
    const int* dst = ei + NE;

    hipMemsetAsync(ws + z1start, 0, 256, stream);          // G0 zero row
    hipMemsetAsync(ws + z2start, 0, z2len, stream);        // G1 zero row + cursor + pool + cntg

    // phase-1 binning || input projection (MFMA)
    k_front<<<NBUK + GB, 512, 0, stream>>>(src, dst, cursor, bucket, x, W0, b0, A);
    // phase-2 ELL build (no sentinel init) || gemmLR layer 0 -> G0, r0
    k_mid<<<NBUK + MGB, 256, 0, stream>>>(bucket, cursor, cnt, ell, A,
                                          (__hip_bfloat16*)G0, Wl, bl, Wr);
    // fused gather0 + gemmLR1: G0 -> G1
    k_gg<<<FB, 512, 0, stream>>>((const uint4*)G0, A, G1, cnt, ell,
                                 Wl + (size_t)1 * 64 * 64, bl + 64, Wr + (size_t)1 * 64 * 64);
    // fused gather1 + gemmLR2: G1 -> G0
    k_gg<<<FB, 512, 0, stream>>>((const uint4*)G1, A, G0, cnt, ell,
                                 Wl + (size_t)2 * 64 * 64, bl + 128, Wr + (size_t)2 * 64 * 64);
    // final gather (layer 2) -> h3 in A
    k_gather<<<3125, 256, 0, stream>>>((const uint4*)G0, A, cnt, ell);

    k_pool<<<256, 256, 0, stream>>>(batch, A, pool, cntg);
    k_out<<<128, 256, 0, stream>>>(pool, cntg, W1, b1, out);
}